// Round 10
// baseline (51.877 us; speedup 1.0000x reference)
//
#include <hip/hip_runtime.h>

// CharacterCNN — f32 in/out, int32 ids. FP16 internal path.
//  A) prep_kernel: [blocks 0..447] split Ht/Hg (hi fp16) + P (hi+lo fp16)
//     into per-nf MFMA-fragment-linear chunks (14,336 B each);
//     [blocks 448..451] conv pattern LUTs -> plain fp16 tables (no key map).
//  B) cnn_kernel: 256 thr / 64 tokens, wave owns 16 tokens. masks ->
//     fp16 table gather + v_pk_max_f16 (ReLU clamp vs 0) -> 14 highway
//     chunks {stage 14KB -> wbuf; barrier; 7 f16 MFMA x2; rcp-sigmoid
//     epilogue in place; barrier} -> 4 P chunks (hi+lo) -> f32 out.

typedef _Float16 f16;
typedef __attribute__((ext_vector_type(8))) _Float16 f16x8;
typedef __attribute__((ext_vector_type(4))) float f32x4;

// table element offsets (f16 units) within ws
#define LC1   0      // 3 x 32
#define LRAW2 96     // 9 x 64
#define LT2   672    // 16 x 64
#define LRAW3 1696   // 27 x 128
#define LT3LO 5152   // 16 x 128
#define LT3HI 7200   // 16 x 128
// fp16 weights start at WOFFB bytes. Element layout (f16 units):
//   highway chunk nf (0..13): nf*7168 + (isG*7+kf)*512 + lane*8 + j
//   P chunk nf (0..3): 100352 + nf*7168 + (isLO*7+kf)*512 + lane*8 + j
#define WOFFB 18944
#define PBASE 100352
#define NWTH  114688
#define WSPLIT_BLOCKS 448
#define LUT_BLOCKS 4
#define CROW 232      // cnn LDS row stride (f16 elems)

__device__ __forceinline__ f16x8 hmax8(f16x8 a, f16x8 b) {
  return __builtin_elementwise_max(a, b);
}

__device__ __forceinline__ f16x8 pin8(f16x8 v) {
  union { f16x8 v; unsigned w[4]; } x; x.v = v;
  asm volatile("" : "+v"(x.w[0]), "+v"(x.w[1]), "+v"(x.w[2]), "+v"(x.w[3]) :: "memory");
  return x.v;
}

// ---------------- prep kernel ----------------
__global__ __launch_bounds__(256) void prep_kernel(
    const float* __restrict__ E,
    const float* __restrict__ W1, const float* __restrict__ b1,
    const float* __restrict__ W2, const float* __restrict__ b2,
    const float* __restrict__ W3, const float* __restrict__ b3,
    const float* __restrict__ HtW, const float* __restrict__ HgW,
    const float* __restrict__ PW,
    f16* __restrict__ tab, f16* __restrict__ wsb)
{
  const int tid = threadIdx.x;
  if (blockIdx.x < WSPLIT_BLOCKS) {
    int idx = blockIdx.x * 256 + tid;
    if (idx < NWTH) {
      int e, isG = 0, isP = 0;
      if (idx < 50176)        { e = idx; }
      else if (idx < 100352)  { e = idx - 50176; isG = 1; }
      else                    { e = idx - 100352; isP = 1; }
      int col = e / 224, k = e - col * 224;
      int nf = col >> 4, kf = k >> 5, kr = k & 31;
      int lane = (col & 15) + ((kr >> 3) << 4), j = kr & 7;
      if (!isP) {
        int off = nf * 7168 + (isG * 7 + kf) * 512 + lane * 8 + j;
        wsb[off] = (f16)(isG ? HgW[e] : HtW[e]);
      } else {
        float w = PW[e];
        f16 hi = (f16)w;
        int off = PBASE + nf * 7168 + kf * 512 + lane * 8 + j;
        wsb[off] = hi;
        wsb[off + 3584] = (f16)(w - (float)hi);   // lo frags at +7*512
      }
    }
    return;
  }

  // ---- LUT part ----
  __shared__ float X[3][16];
  __shared__ float U1[3][32];
  __shared__ float U2[9][64];
  __shared__ float U3[27][128];
  const int gid = (blockIdx.x - WSPLIT_BLOCKS) * 256 + tid;
  const int gsz = LUT_BLOCKS * 256;
  if (tid < 48) { int s = tid >> 4, i = tid & 15; X[s][i] = (s == 0) ? 0.f : E[(s - 1) * 16 + i]; }
  __syncthreads();

  for (int idx = tid; idx < 96; idx += 256) {
    int s = idx >> 5, c = idx & 31;
    float acc = b1[c];
#pragma unroll
    for (int i = 0; i < 16; i++) acc += W1[c * 16 + i] * X[s][i];
    U1[s][c] = acc;
  }
  for (int idx = tid; idx < 576; idx += 256) {
    int p = idx >> 6, c = idx & 63;
    int sa = p / 3, sb = p % 3;
    float acc = b2[c];
#pragma unroll
    for (int i = 0; i < 16; i++)
      acc += W2[c * 32 + i * 2 + 0] * X[sa][i] + W2[c * 32 + i * 2 + 1] * X[sb][i];
    U2[p][c] = acc;
  }
  for (int idx = tid; idx < 3456; idx += 256) {
    int p = idx >> 7, c = idx & 127;
    int sa = p / 9, sb = (p / 3) % 3, sc = p % 3;
    float acc = b3[c];
#pragma unroll
    for (int i = 0; i < 16; i++)
      acc += W3[c * 48 + i * 3 + 0] * X[sa][i]
           + W3[c * 48 + i * 3 + 1] * X[sb][i]
           + W3[c * 48 + i * 3 + 2] * X[sc][i];
    U3[p][c] = acc;
  }
  __syncthreads();

  for (int idx = gid; idx < 96; idx += gsz) {
    int r = idx >> 5, c = idx & 31;
    float v = (r == 0) ? fmaxf(U1[1][c], U1[2][c]) : U1[r][c];
    tab[LC1 + idx] = (f16)v;
  }
  for (int idx = gid; idx < 576; idx += gsz) tab[LRAW2 + idx] = (f16)U2[idx >> 6][idx & 63];
  for (int idx = gid; idx < 3456; idx += gsz) tab[LRAW3 + idx] = (f16)U3[idx >> 7][idx & 127];
  for (int idx = gid; idx < 1024; idx += gsz) {   // T2 subsets: bit b -> (1+(b>>1), 1+(b&1))
    int s = idx >> 6, c = idx & 63;
    float m = -65504.f;
#pragma unroll
    for (int b = 0; b < 4; b++)
      if ((s >> b) & 1) m = fmaxf(m, U2[4 + 3 * (b >> 1) + (b & 1)][c]);
    tab[LT2 + idx] = (f16)m;
  }
  for (int idx = gid; idx < 2048; idx += gsz) {   // T3lo (a=1), T3hi (a=2)
    int s = idx >> 7, c = idx & 127;
    float m = -65504.f;
#pragma unroll
    for (int b = 0; b < 4; b++)
      if ((s >> b) & 1) m = fmaxf(m, U3[13 + 3 * (b >> 1) + (b & 1)][c]);
    tab[LT3LO + idx] = (f16)m;
    m = -65504.f;
#pragma unroll
    for (int b = 0; b < 4; b++)
      if ((s >> b) & 1) m = fmaxf(m, U3[22 + 3 * (b >> 1) + (b & 1)][c]);
    tab[LT3HI + idx] = (f16)m;
  }
}

// ------------- cnn kernel -------------
__global__ __launch_bounds__(256) void cnn_kernel(
    const int* __restrict__ ids,
    const f16* __restrict__ tab, const f16* __restrict__ wsb,
    const float* __restrict__ Htb, const float* __restrict__ Hgb,
    const float* __restrict__ Pb,
    float* __restrict__ out, int n_tok)
{
  __shared__ __attribute__((aligned(16))) f16 cnn[64 * CROW];   // 29,696 B
  __shared__ __attribute__((aligned(16))) f16 wbuf[7168];       // 14,336 B
  __shared__ unsigned masks[64][2];

  const int tid = threadIdx.x;
  const int wave = tid >> 6, lane = tid & 63;
  const int tok0 = blockIdx.x * 64;
  const int rbase = wave * 16;

  // ---- masks: lanes 0..15 compute own wave's 16 tokens ----
  if (lane < 16) {
    int row = rbase + lane;
    unsigned mw = 0, mb = 0;
    if (tok0 + row < n_tok) {
      const int4* idp4 = (const int4*)(ids + (size_t)(tok0 + row) * 20);
      int st[22]; st[0] = 0; st[21] = 0;
#pragma unroll
      for (int q = 0; q < 5; q++) {
        int4 v = idp4[q];
        st[q * 4 + 1] = v.x + 1; st[q * 4 + 2] = v.y + 1;
        st[q * 4 + 3] = v.z + 1; st[q * 4 + 4] = v.w + 1;
      }
      unsigned m3i = 0, m2i = 0, mchar = 0;
#pragma unroll
      for (int l = 1; l <= 18; l++) m3i |= 1u << ((st[l] - 1) * 4 + (st[l + 1] - 1) * 2 + (st[l + 2] - 1));
#pragma unroll
      for (int l = 1; l <= 19; l++) m2i |= 1u << ((st[l] - 1) * 2 + (st[l + 1] - 1));
#pragma unroll
      for (int l = 1; l <= 20; l++) mchar |= 1u << (st[l] - 1);
      int sel = (mchar == 3u) ? 0 : ((mchar & 1u) ? 1 : 2);
      mw = m3i | (m2i << 8) | ((unsigned)sel << 12);
      mb = (unsigned)st[1] | ((unsigned)(st[20] * 3) << 4)
         | ((unsigned)(st[1] * 3 + st[2]) << 8) | ((unsigned)(st[19] * 9 + st[20] * 3) << 16);
    }
    masks[row][0] = mw; masks[row][1] = mb;
  }
  // same-wave LDS write->read ordering via lgkmcnt

  // ---- phase 1: wave fills its own 16 cnn rows; ReLU = max(v, 0) in fp16 ----
  const f16x8 KZ = {0, 0, 0, 0, 0, 0, 0, 0};
  {
    const int tl = lane >> 2, q = lane & 3;
    const int row = rbase + tl;
    const unsigned mw = masks[row][0], mb = masks[row][1];
    const int sel = (mw >> 12) & 3;
    {
      f16x8 v = *(const f16x8*)(tab + LC1 + sel * 32 + q * 8);
      *(f16x8*)&cnn[row * CROW + q * 8] = hmax8(v, KZ);
    }
#pragma unroll
    for (int jj = 0; jj < 2; jj++) {
      int g = q + jj * 4;
      f16x8 v = *(const f16x8*)(tab + LT2 + ((mw >> 8) & 15) * 64 + g * 8);
      v = hmax8(v, *(const f16x8*)(tab + LRAW2 + (mb & 15) * 64 + g * 8));
      v = hmax8(v, *(const f16x8*)(tab + LRAW2 + ((mb >> 4) & 15) * 64 + g * 8));
      *(f16x8*)&cnn[row * CROW + 32 + g * 8] = hmax8(v, KZ);
    }
    const int m3 = mw & 255;
#pragma unroll
    for (int jj = 0; jj < 4; jj++) {
      int g = q + jj * 4;
      f16x8 v = hmax8(*(const f16x8*)(tab + LT3LO + (m3 & 15) * 128 + g * 8),
                      *(const f16x8*)(tab + LT3HI + ((m3 >> 4) & 15) * 128 + g * 8));
      v = hmax8(v, *(const f16x8*)(tab + LRAW3 + ((mb >> 8) & 15) * 128 + g * 8));
      v = hmax8(v, *(const f16x8*)(tab + LRAW3 + ((mb >> 16) & 31) * 128 + g * 8));
      *(f16x8*)&cnn[row * CROW + 96 + g * 8] = hmax8(v, KZ);
    }
  }

  // ---- A-fragments ----
  const int lrow = lane & 15;
  const int kg8 = (lane >> 4) * 8;
  const int rr0 = (lane >> 4) * 4;

  f16x8 af[7];
#pragma unroll
  for (int kf = 0; kf < 7; kf++)
    af[kf] = *(const f16x8*)&cnn[(rbase + lrow) * CROW + kf * 32 + kg8];
#pragma unroll
  for (int kf = 0; kf < 7; kf++) af[kf] = pin8(af[kf]);   // no LDS remat

  // ---- phase 2: 14 highway chunks ----
#pragma unroll
  for (int nf = 0; nf < 14; nf++) {
    const int col = nf * 16 + lrow;
    uint2 stg[7];
    {
      const uint2* src = (const uint2*)(wsb + nf * 7168) + tid;
#pragma unroll
      for (int r = 0; r < 7; r++) stg[r] = src[r * 256];
    }
    const float bt = Htb[col], bg = Hgb[col];   // overlaps with staging
    {
      uint2* dst = (uint2*)wbuf + tid;
#pragma unroll
      for (int r = 0; r < 7; r++) dst[r * 256] = stg[r];
    }
    __syncthreads();
    f32x4 aT = {bt, bt, bt, bt};
    f32x4 aG = {bg, bg, bg, bg};
#pragma unroll
    for (int kf = 0; kf < 7; kf++) {
      f16x8 wTv = *(const f16x8*)&wbuf[kf * 512 + lane * 8];
      f16x8 wGv = *(const f16x8*)&wbuf[(7 + kf) * 512 + lane * 8];
      aT = __builtin_amdgcn_mfma_f32_16x16x32_f16(af[kf], wTv, aT, 0, 0, 0);
      aG = __builtin_amdgcn_mfma_f32_16x16x32_f16(af[kf], wGv, aG, 0, 0, 0);
    }
#pragma unroll
    for (int r = 0; r < 4; r++) {
      int row = rbase + rr0 + r;
      float t  = fmaxf(aT[r], 0.f);
      float gg = __builtin_amdgcn_rcpf(1.f + __expf(-aG[r]));
      float cv = (float)cnn[row * CROW + col];
      cnn[row * CROW + col] = (f16)(cv + gg * (t - cv));   // own rows only
    }
    __syncthreads();
  }

  // ---- phase 3: reload hw A-frags, 4 P chunks (hi+lo) ----
  f16x8 ah[7];
#pragma unroll
  for (int kf = 0; kf < 7; kf++)
    ah[kf] = *(const f16x8*)&cnn[(rbase + lrow) * CROW + kf * 32 + kg8];
#pragma unroll
  for (int kf = 0; kf < 7; kf++) ah[kf] = pin8(ah[kf]);

#pragma unroll
  for (int nf = 0; nf < 4; nf++) {
    const int col = nf * 16 + lrow;
    uint2 stg[7];
    {
      const uint2* src = (const uint2*)(wsb + PBASE + nf * 7168) + tid;
#pragma unroll
      for (int r = 0; r < 7; r++) stg[r] = src[r * 256];
    }
    const float bp = Pb[col];
    {
      uint2* dst = (uint2*)wbuf + tid;
#pragma unroll
      for (int r = 0; r < 7; r++) dst[r * 256] = stg[r];
    }
    __syncthreads();
    f32x4 ac = {bp, bp, bp, bp};
#pragma unroll
    for (int kf = 0; kf < 7; kf++) {
      f16x8 wh = *(const f16x8*)&wbuf[kf * 512 + lane * 8];
      f16x8 wl = *(const f16x8*)&wbuf[(7 + kf) * 512 + lane * 8];
      ac = __builtin_amdgcn_mfma_f32_16x16x32_f16(ah[kf], wh, ac, 0, 0, 0);
      ac = __builtin_amdgcn_mfma_f32_16x16x32_f16(ah[kf], wl, ac, 0, 0, 0);
    }
#pragma unroll
    for (int r = 0; r < 4; r++) {
      int row = rbase + rr0 + r;
      if (tok0 + row < n_tok) out[(size_t)(tok0 + row) * 64 + col] = ac[r];
    }
    __syncthreads();
  }
}

extern "C" void kernel_launch(void* const* d_in, const int* in_sizes, int n_in,
                              void* d_out, int out_size, void* d_ws, size_t ws_size,
                              hipStream_t stream) {
  const int*   ids = (const int*)d_in[0];
  const float* E   = (const float*)d_in[1];
  const float* W1  = (const float*)d_in[2];
  const float* b1  = (const float*)d_in[3];
  const float* W2  = (const float*)d_in[4];
  const float* b2  = (const float*)d_in[5];
  const float* W3  = (const float*)d_in[6];
  const float* b3  = (const float*)d_in[7];
  const float* HtW = (const float*)d_in[8];
  const float* Htb = (const float*)d_in[9];
  const float* HgW = (const float*)d_in[10];
  const float* Hgb = (const float*)d_in[11];
  const float* PW  = (const float*)d_in[12];
  const float* Pb  = (const float*)d_in[13];
  float* out = (float*)d_out;
  f16* tab = (f16*)d_ws;
  f16* wsb = (f16*)((char*)d_ws + WOFFB);

  const int n_tok = in_sizes[0] / 20;
  prep_kernel<<<WSPLIT_BLOCKS + LUT_BLOCKS, 256, 0, stream>>>(
      E, W1, b1, W2, b2, W3, b3, HtW, HgW, PW, tab, wsb);
  cnn_kernel<<<(n_tok + 63) / 64, 256, 0, stream>>>(
      ids, tab, wsb, Htb, Hgb, Pb, out, n_tok);
}

// Round 11
// 46.259 us; speedup vs baseline: 1.1214x; 1.1214x over previous
//
#include <hip/hip_runtime.h>

// CharacterCNN — f32 in/out, int32 ids. FP16 internal path.
//  A) prep_kernel: [blocks 0..447] split Ht/Hg (fp16) + P (hi+lo fp16)
//     into per-nf MFMA-fragment-linear chunks (14,336 B each);
//     [blocks 448..451] conv pattern LUTs -> plain fp16 tables.
//  B) cnn_kernel: 256 thr / 64 tokens, wave owns 16 tokens. masks ->
//     fp16 table gather + v_pk_max_f16 -> 18-chunk software pipeline:
//     {issue global_load_lds(16B) for chunk c+1 -> other wbuf; vmcnt(own);
//      raw s_barrier; compute chunk c (14 MFMA + epilogue)} -> f32 out.
//     Counted vmcnt never drains to 0 inside the loop (T3/T4 pattern).

typedef _Float16 f16;
typedef __attribute__((ext_vector_type(8))) _Float16 f16x8;
typedef __attribute__((ext_vector_type(4))) float f32x4;

typedef const unsigned int __attribute__((address_space(1)))* gas_t;
typedef unsigned int __attribute__((address_space(3)))* las_t;

// table element offsets (f16 units) within ws
#define LC1   0      // 3 x 32
#define LRAW2 96     // 9 x 64
#define LT2   672    // 16 x 64
#define LRAW3 1696   // 27 x 128
#define LT3LO 5152   // 16 x 128
#define LT3HI 7200   // 16 x 128
// fp16 weights start at WOFFB bytes. Element layout (f16 units):
//   highway chunk nf (0..13): nf*7168 + (isG*7+kf)*512 + lane*8 + j
//   P chunk nf (0..3): 100352 + nf*7168 + (isLO*7+kf)*512 + lane*8 + j
#define WOFFB 18944
#define PBASE 100352
#define NWTH  114688
#define WSPLIT_BLOCKS 448
#define LUT_BLOCKS 4
#define CROW 232      // cnn LDS row stride (f16 elems)

#define VM4 asm volatile("s_waitcnt vmcnt(4)" ::: "memory")
#define VM3 asm volatile("s_waitcnt vmcnt(3)" ::: "memory")
#define VM0 asm volatile("s_waitcnt vmcnt(0)" ::: "memory")
#define SBAR __builtin_amdgcn_sched_barrier(0)
#define BARR __builtin_amdgcn_s_barrier()

__device__ __forceinline__ f16x8 hmax8(f16x8 a, f16x8 b) {
  return __builtin_elementwise_max(a, b);
}

__device__ __forceinline__ f16x8 pin8(f16x8 v) {
  union { f16x8 v; unsigned w[4]; } x; x.v = v;
  asm volatile("" : "+v"(x.w[0]), "+v"(x.w[1]), "+v"(x.w[2]), "+v"(x.w[3]) :: "memory");
  return x.v;
}

// stage one 14,336-B chunk: waves 0,1 issue 4 x 1KB wave-loads; waves 2,3
// issue 3. Direct global->LDS, 16B/lane, linear both sides.
__device__ __forceinline__ void stage_chunk(const f16* __restrict__ src,
                                            f16* dst, int wave, int lane) {
  const char* s = (const char*)src + lane * 16;
  char* d = (char*)dst;
#pragma unroll
  for (int r = 0; r < 3; r++) {
    int j = wave + r * 4;
    __builtin_amdgcn_global_load_lds((gas_t)(s + j * 1024),
                                     (las_t)(d + j * 1024), 16, 0, 0);
  }
  if (wave < 2) {
    int j = wave + 12;
    __builtin_amdgcn_global_load_lds((gas_t)(s + j * 1024),
                                     (las_t)(d + j * 1024), 16, 0, 0);
  }
}

// ---------------- prep kernel ----------------
__global__ __launch_bounds__(256) void prep_kernel(
    const float* __restrict__ E,
    const float* __restrict__ W1, const float* __restrict__ b1,
    const float* __restrict__ W2, const float* __restrict__ b2,
    const float* __restrict__ W3, const float* __restrict__ b3,
    const float* __restrict__ HtW, const float* __restrict__ HgW,
    const float* __restrict__ PW,
    f16* __restrict__ tab, f16* __restrict__ wsb)
{
  const int tid = threadIdx.x;
  if (blockIdx.x < WSPLIT_BLOCKS) {
    int idx = blockIdx.x * 256 + tid;
    if (idx < NWTH) {
      int e, isG = 0, isP = 0;
      if (idx < 50176)        { e = idx; }
      else if (idx < 100352)  { e = idx - 50176; isG = 1; }
      else                    { e = idx - 100352; isP = 1; }
      int col = e / 224, k = e - col * 224;
      int nf = col >> 4, kf = k >> 5, kr = k & 31;
      int lane = (col & 15) + ((kr >> 3) << 4), j = kr & 7;
      if (!isP) {
        int off = nf * 7168 + (isG * 7 + kf) * 512 + lane * 8 + j;
        wsb[off] = (f16)(isG ? HgW[e] : HtW[e]);
      } else {
        float w = PW[e];
        f16 hi = (f16)w;
        int off = PBASE + nf * 7168 + kf * 512 + lane * 8 + j;
        wsb[off] = hi;
        wsb[off + 3584] = (f16)(w - (float)hi);   // lo frags at +7*512
      }
    }
    return;
  }

  // ---- LUT part ----
  __shared__ float X[3][16];
  __shared__ float U1[3][32];
  __shared__ float U2[9][64];
  __shared__ float U3[27][128];
  const int gid = (blockIdx.x - WSPLIT_BLOCKS) * 256 + tid;
  const int gsz = LUT_BLOCKS * 256;
  if (tid < 48) { int s = tid >> 4, i = tid & 15; X[s][i] = (s == 0) ? 0.f : E[(s - 1) * 16 + i]; }
  __syncthreads();

  for (int idx = tid; idx < 96; idx += 256) {
    int s = idx >> 5, c = idx & 31;
    float acc = b1[c];
#pragma unroll
    for (int i = 0; i < 16; i++) acc += W1[c * 16 + i] * X[s][i];
    U1[s][c] = acc;
  }
  for (int idx = tid; idx < 576; idx += 256) {
    int p = idx >> 6, c = idx & 63;
    int sa = p / 3, sb = p % 3;
    float acc = b2[c];
#pragma unroll
    for (int i = 0; i < 16; i++)
      acc += W2[c * 32 + i * 2 + 0] * X[sa][i] + W2[c * 32 + i * 2 + 1] * X[sb][i];
    U2[p][c] = acc;
  }
  for (int idx = tid; idx < 3456; idx += 256) {
    int p = idx >> 7, c = idx & 127;
    int sa = p / 9, sb = (p / 3) % 3, sc = p % 3;
    float acc = b3[c];
#pragma unroll
    for (int i = 0; i < 16; i++)
      acc += W3[c * 48 + i * 3 + 0] * X[sa][i]
           + W3[c * 48 + i * 3 + 1] * X[sb][i]
           + W3[c * 48 + i * 3 + 2] * X[sc][i];
    U3[p][c] = acc;
  }
  __syncthreads();

  for (int idx = gid; idx < 96; idx += gsz) {
    int r = idx >> 5, c = idx & 31;
    float v = (r == 0) ? fmaxf(U1[1][c], U1[2][c]) : U1[r][c];
    tab[LC1 + idx] = (f16)v;
  }
  for (int idx = gid; idx < 576; idx += gsz) tab[LRAW2 + idx] = (f16)U2[idx >> 6][idx & 63];
  for (int idx = gid; idx < 3456; idx += gsz) tab[LRAW3 + idx] = (f16)U3[idx >> 7][idx & 127];
  for (int idx = gid; idx < 1024; idx += gsz) {
    int s = idx >> 6, c = idx & 63;
    float m = -65504.f;
#pragma unroll
    for (int b = 0; b < 4; b++)
      if ((s >> b) & 1) m = fmaxf(m, U2[4 + 3 * (b >> 1) + (b & 1)][c]);
    tab[LT2 + idx] = (f16)m;
  }
  for (int idx = gid; idx < 2048; idx += gsz) {
    int s = idx >> 7, c = idx & 127;
    float m = -65504.f;
#pragma unroll
    for (int b = 0; b < 4; b++)
      if ((s >> b) & 1) m = fmaxf(m, U3[13 + 3 * (b >> 1) + (b & 1)][c]);
    tab[LT3LO + idx] = (f16)m;
    m = -65504.f;
#pragma unroll
    for (int b = 0; b < 4; b++)
      if ((s >> b) & 1) m = fmaxf(m, U3[22 + 3 * (b >> 1) + (b & 1)][c]);
    tab[LT3HI + idx] = (f16)m;
  }
}

// ------------- cnn kernel -------------
__global__ __launch_bounds__(256) void cnn_kernel(
    const int* __restrict__ ids,
    const f16* __restrict__ tab, const f16* __restrict__ wsb,
    const float* __restrict__ Htb, const float* __restrict__ Hgb,
    const float* __restrict__ Pb,
    float* __restrict__ out, int n_tok)
{
  __shared__ __attribute__((aligned(16))) f16 cnn[64 * CROW];   // 29,696 B
  __shared__ __attribute__((aligned(16))) f16 wbufA[7168];      // 14,336 B
  __shared__ __attribute__((aligned(16))) f16 wbufB[7168];      // 14,336 B
  __shared__ unsigned masks[64][2];

  const int tid = threadIdx.x;
  const int wave = tid >> 6, lane = tid & 63;
  const int tok0 = blockIdx.x * 64;
  const int rbase = wave * 16;
  const int lrow = lane & 15;
  const int kg8 = (lane >> 4) * 8;
  const int rr0 = (lane >> 4) * 4;

  // ---- bias preload (deep in vmcnt queue; drained by first counted wait) ----
  float btv[14], bgv[14], bpv[4];
#pragma unroll
  for (int nf = 0; nf < 14; nf++) {
    btv[nf] = Htb[nf * 16 + lrow];
    bgv[nf] = Hgb[nf * 16 + lrow];
  }
#pragma unroll
  for (int nf = 0; nf < 4; nf++) bpv[nf] = Pb[nf * 16 + lrow];

  // ---- masks: lanes 0..15 compute own wave's 16 tokens ----
  if (lane < 16) {
    int row = rbase + lane;
    unsigned mw = 0, mb = 0;
    if (tok0 + row < n_tok) {
      const int4* idp4 = (const int4*)(ids + (size_t)(tok0 + row) * 20);
      int st[22]; st[0] = 0; st[21] = 0;
#pragma unroll
      for (int q = 0; q < 5; q++) {
        int4 v = idp4[q];
        st[q * 4 + 1] = v.x + 1; st[q * 4 + 2] = v.y + 1;
        st[q * 4 + 3] = v.z + 1; st[q * 4 + 4] = v.w + 1;
      }
      unsigned m3i = 0, m2i = 0, mchar = 0;
#pragma unroll
      for (int l = 1; l <= 18; l++) m3i |= 1u << ((st[l] - 1) * 4 + (st[l + 1] - 1) * 2 + (st[l + 2] - 1));
#pragma unroll
      for (int l = 1; l <= 19; l++) m2i |= 1u << ((st[l] - 1) * 2 + (st[l + 1] - 1));
#pragma unroll
      for (int l = 1; l <= 20; l++) mchar |= 1u << (st[l] - 1);
      int sel = (mchar == 3u) ? 0 : ((mchar & 1u) ? 1 : 2);
      mw = m3i | (m2i << 8) | ((unsigned)sel << 12);
      mb = (unsigned)st[1] | ((unsigned)(st[20] * 3) << 4)
         | ((unsigned)(st[1] * 3 + st[2]) << 8) | ((unsigned)(st[19] * 9 + st[20] * 3) << 16);
    }
    masks[row][0] = mw; masks[row][1] = mb;
  }
  // same-wave LDS write->read ordering via lgkmcnt

  // ---- phase 1: wave fills its own 16 cnn rows; ReLU = max(v, 0) ----
  const f16x8 KZ = {0, 0, 0, 0, 0, 0, 0, 0};
  {
    const int tl = lane >> 2, q = lane & 3;
    const int row = rbase + tl;
    const unsigned mw = masks[row][0], mb = masks[row][1];
    const int sel = (mw >> 12) & 3;
    {
      f16x8 v = *(const f16x8*)(tab + LC1 + sel * 32 + q * 8);
      *(f16x8*)&cnn[row * CROW + q * 8] = hmax8(v, KZ);
    }
#pragma unroll
    for (int jj = 0; jj < 2; jj++) {
      int g = q + jj * 4;
      f16x8 v = *(const f16x8*)(tab + LT2 + ((mw >> 8) & 15) * 64 + g * 8);
      v = hmax8(v, *(const f16x8*)(tab + LRAW2 + (mb & 15) * 64 + g * 8));
      v = hmax8(v, *(const f16x8*)(tab + LRAW2 + ((mb >> 4) & 15) * 64 + g * 8));
      *(f16x8*)&cnn[row * CROW + 32 + g * 8] = hmax8(v, KZ);
    }
    const int m3 = mw & 255;
#pragma unroll
    for (int jj = 0; jj < 4; jj++) {
      int g = q + jj * 4;
      f16x8 v = hmax8(*(const f16x8*)(tab + LT3LO + (m3 & 15) * 128 + g * 8),
                      *(const f16x8*)(tab + LT3HI + ((m3 >> 4) & 15) * 128 + g * 8));
      v = hmax8(v, *(const f16x8*)(tab + LRAW3 + ((mb >> 8) & 15) * 128 + g * 8));
      v = hmax8(v, *(const f16x8*)(tab + LRAW3 + ((mb >> 16) & 31) * 128 + g * 8));
      *(f16x8*)&cnn[row * CROW + 96 + g * 8] = hmax8(v, KZ);
    }
  }

  // ---- A-fragments (pinned: cnn rows get overwritten in-place later) ----
  f16x8 af[7];
#pragma unroll
  for (int kf = 0; kf < 7; kf++)
    af[kf] = *(const f16x8*)&cnn[(rbase + lrow) * CROW + kf * 32 + kg8];
#pragma unroll
  for (int kf = 0; kf < 7; kf++) af[kf] = pin8(af[kf]);

  f16x8 ah[7];   // hw fragments, loaded at chunk 14

  // ---- 18-chunk pipeline: 14 highway (T+G) + 4 projection (hi+lo) ----
  stage_chunk(wsb, wbufA, wave, lane);   // chunk 0
#pragma unroll
  for (int ci = 0; ci < 18; ci++) {
    f16* cur = (ci & 1) ? wbufB : wbufA;
    f16* nxt = (ci & 1) ? wbufA : wbufB;
    if (ci + 1 < 18) {
      const f16* src = (ci + 1 < 14) ? (wsb + (ci + 1) * 7168)
                                     : (wsb + PBASE + (ci + 1 - 14) * 7168);
      stage_chunk(src, nxt, wave, lane);
      if (wave < 2) { VM4; } else { VM3; }
    } else {
      VM0;
    }
    SBAR; BARR; SBAR;

    if (ci < 14) {
      const int col = ci * 16 + lrow;
      const float bt = btv[ci], bg = bgv[ci];
      f32x4 aT = {bt, bt, bt, bt};
      f32x4 aG = {bg, bg, bg, bg};
#pragma unroll
      for (int kf = 0; kf < 7; kf++) {
        f16x8 wTv = *(const f16x8*)&cur[kf * 512 + lane * 8];
        f16x8 wGv = *(const f16x8*)&cur[(7 + kf) * 512 + lane * 8];
        aT = __builtin_amdgcn_mfma_f32_16x16x32_f16(af[kf], wTv, aT, 0, 0, 0);
        aG = __builtin_amdgcn_mfma_f32_16x16x32_f16(af[kf], wGv, aG, 0, 0, 0);
      }
#pragma unroll
      for (int r = 0; r < 4; r++) {
        int row = rbase + rr0 + r;
        float t  = fmaxf(aT[r], 0.f);
        float gg = __builtin_amdgcn_rcpf(1.f + __expf(-aG[r]));
        float cv = (float)cnn[row * CROW + col];
        cnn[row * CROW + col] = (f16)(cv + gg * (t - cv));   // own rows only
      }
    } else {
      if (ci == 14) {   // hw complete for this wave's rows; reload A-frags
#pragma unroll
        for (int kf = 0; kf < 7; kf++)
          ah[kf] = *(const f16x8*)&cnn[(rbase + lrow) * CROW + kf * 32 + kg8];
      }
      const int pc = ci - 14;
      const int col = pc * 16 + lrow;
      const float bp = bpv[pc];
      f32x4 ac = {bp, bp, bp, bp};
#pragma unroll
      for (int kf = 0; kf < 7; kf++) {
        f16x8 wh = *(const f16x8*)&cur[kf * 512 + lane * 8];
        f16x8 wl = *(const f16x8*)&cur[3584 + kf * 512 + lane * 8];
        ac = __builtin_amdgcn_mfma_f32_16x16x32_f16(ah[kf], wh, ac, 0, 0, 0);
        ac = __builtin_amdgcn_mfma_f32_16x16x32_f16(ah[kf], wl, ac, 0, 0, 0);
      }
#pragma unroll
      for (int r = 0; r < 4; r++) {
        int row = rbase + rr0 + r;
        if (tok0 + row < n_tok) out[(size_t)(tok0 + row) * 64 + col] = ac[r];
      }
    }
    asm volatile("" ::: "memory");
    BARR; SBAR;   // all waves done with cur before it is restaged
  }
}

extern "C" void kernel_launch(void* const* d_in, const int* in_sizes, int n_in,
                              void* d_out, int out_size, void* d_ws, size_t ws_size,
                              hipStream_t stream) {
  const int*   ids = (const int*)d_in[0];
  const float* E   = (const float*)d_in[1];
  const float* W1  = (const float*)d_in[2];
  const float* b1  = (const float*)d_in[3];
  const float* W2  = (const float*)d_in[4];
  const float* b2  = (const float*)d_in[5];
  const float* W3  = (const float*)d_in[6];
  const float* b3  = (const float*)d_in[7];
  const float* HtW = (const float*)d_in[8];
  const float* Htb = (const float*)d_in[9];
  const float* HgW = (const float*)d_in[10];
  const float* Hgb = (const float*)d_in[11];
  const float* PW  = (const float*)d_in[12];
  const float* Pb  = (const float*)d_in[13];
  float* out = (float*)d_out;
  f16* tab = (f16*)d_ws;
  f16* wsb = (f16*)((char*)d_ws + WOFFB);

  const int n_tok = in_sizes[0] / 20;
  prep_kernel<<<WSPLIT_BLOCKS + LUT_BLOCKS, 256, 0, stream>>>(
      E, W1, b1, W2, b2, W3, b3, HtW, HgW, PW, tab, wsb);
  cnn_kernel<<<(n_tok + 63) / 64, 256, 0, stream>>>(
      ids, tab, wsb, Htb, Hgb, Pb, out, n_tok);
}